// Round 11
// baseline (2541.505 us; speedup 1.0000x reference)
//
#include <hip/hip_runtime.h>

#define DEG 17
#define NSTEPS 32
#define HD 96

// ---- workspace float offsets ----
#define WS_U0     0          // 196608
#define WS_BAR    196608     // 256 ints (16 counters spaced 16 apart)
#define WS_U1     196864     // 196608
#define WS_XIN    393472     // 98304
#define WS_GX     491776     // 393216
#define WS_LOSSP  884992     // 16384 floats (32 steps * 512)
#define WS_CNTP   901376     // 16384 ints

// ---- LDS layout (floats), ONE block = 2 nodes, 77,088 B -> 2 blocks/CU ----
#define W1L    0        // 9216  [96][96]  (W2 is streamed from L2)
#define MSGB   9216     // 288
#define M0B    9504     // 96
#define MSGH2  9600     // 384  [192 k][2 m] (msg k<96 rewritten each step; h k>=96 persists)
#define GATES2 9984     // 768  [2][384]
#define H2T2   10752    // 192  [96][2]
#define SLC2   10944    // 192  [2][96] cell state (persistent)
#define LGT    11136    // 32
#define NBRI   11168    // 40 ints
#define S3T    11208    // 384  [96 j][2 nd][2 slot]
#define Z1     11592    // 3840 [96][40]; overlays: P3[32][96]=3072, PL[16][384]=6144, PU[32][192]=6144
#define Z2     15432    // 3840 [96][40]  (PL/PU overflow into here; dead after phase 3)
#define SMTOT  19272    // 77,088 B

// ---------------- init1: embedding + input MLP -> xin; u0 self-half = msg0_b
__global__ void init_kernel(
    const int* __restrict__ x,
    const float* __restrict__ digit_emb,
    const float* __restrict__ row_emb,
    const float* __restrict__ col_emb,
    const float* __restrict__ in0_W,
    const float* __restrict__ in0_b,
    const float* __restrict__ in_Ws,
    const float* __restrict__ in_bs,
    const float* __restrict__ msg0_b,
    float* __restrict__ xin,
    float* __restrict__ u0)
{
  const int node = blockIdx.x;
  const int j = threadIdx.x;
  const int n = node & 63;
  const int r = n >> 3, c = n & 7;
  __shared__ float feat[48];
  __shared__ float za[HD];
  __shared__ float zb[HD];
  if (j < 16)      feat[j] = digit_emb[x[node]*16 + j];
  else if (j < 32) feat[j] = row_emb[r*16 + (j-16)];
  else if (j < 48) feat[j] = col_emb[c*16 + (j-32)];
  u0[node*192 + 96 + j] = msg0_b[j];
  __syncthreads();
  float a = in0_b[j];
  for (int k = 0; k < 48; ++k) a = fmaf(feat[k], in0_W[k*HD + j], a);
  za[j] = fmaxf(a, 0.f);
  __syncthreads();
  a = in_bs[j];
  for (int k = 0; k < HD; ++k) a = fmaf(za[k], in_Ws[k*HD + j], a);
  zb[j] = fmaxf(a, 0.f);
  __syncthreads();
  a = in_bs[HD + j];
  for (int k = 0; k < HD; ++k) a = fmaf(zb[k], in_Ws[9216 + k*HD + j], a);
  za[j] = fmaxf(a, 0.f);
  __syncthreads();
  a = in_bs[2*HD + j];
  for (int k = 0; k < HD; ++k) a = fmaf(za[k], in_Ws[2*9216 + k*HD + j], a);
  xin[node*HD + j] = a;
}

// ---------------- init2: gx = xin @ W_ih[96:192] + b_ih + b_hh (one-time)
__global__ __launch_bounds__(384) void gx_kernel(
    const float* __restrict__ xin, const float* __restrict__ W_ih,
    const float* __restrict__ b_ih, const float* __restrict__ b_hh,
    float* __restrict__ gx)
{
  __shared__ float xs[4*HD];
  const int tid = threadIdx.x;
  const int base = blockIdx.x * 4;
  {
    const int m = tid / HD, k = tid - m*HD;
    xs[m*HD + k] = xin[(base+m)*HD + k];
  }
  __syncthreads();
  const int j = tid;  // 0..383
  float a0 = b_ih[j] + b_hh[j], a1 = a0, a2 = a0, a3 = a0;
  for (int k = 0; k < HD; ++k) {
    const float w = W_ih[(96+k)*384 + j];
    a0 = fmaf(xs[k], w, a0);
    a1 = fmaf(xs[HD+k], w, a1);
    a2 = fmaf(xs[2*HD+k], w, a2);
    a3 = fmaf(xs[3*HD+k], w, a3);
  }
  gx[(base+0)*384 + j] = a0;
  gx[(base+1)*384 + j] = a1;
  gx[(base+2)*384 + j] = a2;
  gx[(base+3)*384 + j] = a3;
}

// ---------------- persistent solver: 512 blocks x 512 thr, 2 blocks/CU (4 waves/SIMD) ----------------
// 512-thread blocks historically compile at VGPR=128 spill-free (r2-r7); 2 independent
// blocks per CU provide the cross-block latency hiding the 1-block configs lacked.
// LDS 77KB/block (W1 resident; W2/W3/Wih/Whh/msg0_W/gx/pred_W streamed from L2 --
// r7 measured weight-stream bandwidth as non-binding).
__global__ __launch_bounds__(512, 4) void solve_kernel(
    const int* __restrict__ edges,
    const float* __restrict__ msg0_W, const float* __restrict__ msg0_b,
    const float* __restrict__ msg_Ws, const float* __restrict__ msg_bs,
    const float* __restrict__ W_ih, const float* __restrict__ W_hh,
    const float* __restrict__ pred_W, const float* __restrict__ pred_b,
    const int* __restrict__ target,
    const float* __restrict__ gx,
    float* __restrict__ u0, float* __restrict__ u1,
    int* bar,
    float* __restrict__ lossP, int* __restrict__ cntP,
    float* __restrict__ final_pred_out)
{
  __shared__ float sm[SMTOT];

  const int tid = threadIdx.x;
  const int blk = blockIdx.x;
  const int bb  = blk & 15;          // batch; blocks == bb (mod 16) -> same XCD under %8 round-robin
  const int grp = blk >> 4;          // 0..31
  const int base = bb*64 + grp*2;    // first node of block (2 nodes)

  int* const nbrs = (int*)(sm + NBRI);
  const float* const W2g = msg_Ws + 9216;
  const float* const W3g = msg_Ws + 2*9216;

  // ===== one-time LDS fill =====
  for (int i = tid*4; i < 9216; i += 2048)
    *(float4*)&sm[W1L + i] = *(const float4*)&msg_Ws[i];
  if (tid < 288) sm[MSGB + tid] = msg_bs[tid];
  if (tid < 96)  sm[M0B + tid]  = msg0_b[tid];
  if (tid < 192) {
    sm[SLC2 + tid] = 0.f;            // cell state [2][96]
    sm[MSGH2 + 192 + tid] = 0.f;     // h slots (k=96..191)
  }
  if (tid < 40) {
    const int m = tid / 20, r = tid % 20;
    nbrs[tid] = (r < DEG) ? (bb*64 + edges[(grp*2 + m)*DEG + r])*192 : -1;
  }
  __syncthreads();

  const float* uP = u0;
  float*       uN = u1;

  for (int st = 0; st < NSTEPS; ++st) {
    // ===== phase 1: z1 gather (480 thr) + s3t zero (32 thr) =====
    if (tid < 480) {
      const int row = tid % 40;      // m*20 + r
      const int kc  = tid / 40;      // 0..11, 8 k each
      const int m = row / 20;
      const int k0 = kc * 8;
      const int nb = nbrs[row];
      if (nb >= 0) {
        const float* ue = uP + nb + k0;
        const float* us = uP + (base+m)*192 + 96 + k0;
        #pragma unroll
        for (int t = 0; t < 2; ++t) {
          const float4 a = *(const float4*)(ue + 4*t);
          const float4 b = *(const float4*)(us + 4*t);
          sm[Z1 + (k0+4*t+0)*40 + row] = fmaxf(a.x + b.x, 0.f);
          sm[Z1 + (k0+4*t+1)*40 + row] = fmaxf(a.y + b.y, 0.f);
          sm[Z1 + (k0+4*t+2)*40 + row] = fmaxf(a.z + b.z, 0.f);
          sm[Z1 + (k0+4*t+3)*40 + row] = fmaxf(a.w + b.w, 0.f);
        }
      } else {
        #pragma unroll
        for (int t = 0; t < 8; ++t) sm[Z1 + (k0+t)*40 + row] = 0.f;
      }
    } else {
      const int i = tid - 480;       // 32 threads zero S3T[384]
      #pragma unroll
      for (int t = 0; t < 12; ++t) sm[S3T + i*12 + t] = 0.f;
    }
    __syncthreads();

    // ===== phase 2: GEMM1 z2 = relu(z1 @ W1 + b1), W1 in LDS =====
    if (tid < 480) {
      const int jg = tid % 24, dg = tid / 24;   // 4 cols, 2 rows
      const int j4 = jg*4, d2 = dg*2;
      float acc[2][4] = {{0.f}};
      #pragma unroll 4
      for (int k = 0; k < 96; ++k) {
        const float2 z = *(const float2*)&sm[Z1 + k*40 + d2];
        const float4 w = *(const float4*)&sm[W1L + k*96 + j4];
        const float ze[2] = {z.x, z.y};
        const float we[4] = {w.x, w.y, w.z, w.w};
        #pragma unroll
        for (int dd = 0; dd < 2; ++dd)
          #pragma unroll
          for (int jj = 0; jj < 4; ++jj)
            acc[dd][jj] = fmaf(ze[dd], we[jj], acc[dd][jj]);
      }
      #pragma unroll
      for (int jj = 0; jj < 4; ++jj) {
        const float b1 = sm[MSGB + j4 + jj];
        float2 q;
        q.x = fmaxf(acc[0][jj] + b1, 0.f);
        q.y = fmaxf(acc[1][jj] + b1, 0.f);
        *(float2*)&sm[Z2 + (j4+jj)*40 + d2] = q;
      }
    }
    __syncthreads();

    // ===== phase 3: GEMM2 (stream W2 from L2) + relu + masked row-sum -> s3t =====
    if (tid < 480) {
      const int jg = tid % 24, dg = tid / 24;
      const int j4 = jg*4, d2 = dg*2;
      float acc[2][4] = {{0.f}};
      #pragma unroll 4
      for (int k = 0; k < 96; ++k) {
        const float2 z = *(const float2*)&sm[Z2 + k*40 + d2];
        const float4 w = *(const float4*)&W2g[k*96 + j4];
        const float ze[2] = {z.x, z.y};
        const float we[4] = {w.x, w.y, w.z, w.w};
        #pragma unroll
        for (int dd = 0; dd < 2; ++dd)
          #pragma unroll
          for (int jj = 0; jj < 4; ++jj)
            acc[dd][jj] = fmaf(ze[dd], we[jj], acc[dd][jj]);
      }
      const int nd = dg / 10, slot = dg & 1;
      const int r0 = d2 - nd*20;     // rows r0, r0+1 of this node
      #pragma unroll
      for (int jj = 0; jj < 4; ++jj) {
        const float b2 = sm[MSGB + 96 + j4 + jj];
        float p = 0.f;
        #pragma unroll
        for (int dd = 0; dd < 2; ++dd)
          if (r0 + dd < DEG) p += fmaxf(acc[dd][jj] + b2, 0.f);
        atomicAdd(&sm[S3T + (j4+jj)*4 + nd*2 + slot], p);
      }
    }
    __syncthreads();

    // ===== phase 4a: GEMM3 partials (stream W3) =====
    if (tid < 384) {
      const int jg = tid % 24, kq = tid / 24;   // kq 0..15, 6 k each
      const int j4 = jg*4, k0 = kq*6;
      float acc[2][4] = {{0.f}};
      #pragma unroll
      for (int kk = 0; kk < 6; ++kk) {
        const int k = k0 + kk;
        const float4 sv = *(const float4*)&sm[S3T + k*4];
        const float se[2] = {sv.x + sv.y, sv.z + sv.w};   // sum the 2 slots
        const float4 wv = *(const float4*)&W3g[k*96 + j4];
        const float we[4] = {wv.x, wv.y, wv.z, wv.w};
        #pragma unroll
        for (int m = 0; m < 2; ++m)
          #pragma unroll
          for (int jj = 0; jj < 4; ++jj)
            acc[m][jj] = fmaf(se[m], we[jj], acc[m][jj]);
      }
      #pragma unroll
      for (int m = 0; m < 2; ++m) {
        float4 q = {acc[m][0], acc[m][1], acc[m][2], acc[m][3]};
        *(float4*)&sm[Z1 + (kq*2 + m)*96 + j4] = q;    // P3 overlay [32][96]
      }
    }
    __syncthreads();
    // ===== phase 4b: reduce -> msgh msg-half =====
    if (tid < 192) {
      const int m = tid / 96, j = tid % 96;
      float v = 17.f * sm[MSGB + 192 + j];
      #pragma unroll
      for (int kq = 0; kq < 16; ++kq) v += sm[Z1 + (kq*2 + m)*96 + j];
      sm[MSGH2 + j*2 + m] = v;
    }
    __syncthreads();

    // ===== phase 5: LSTM GEMM gates partials (stream Wih/Whh) =====
    {
      const int jg = tid & 63, kq = tid >> 6;   // 6 cols, kq 0..7 x 24k
      const int j6 = jg*6, k0 = kq*24;
      const float* Wb = (kq < 4) ? (W_ih + (size_t)k0*384 + j6)
                                 : (W_hh + (size_t)(k0-96)*384 + j6);
      float acc[2][6] = {{0.f}};
      #pragma unroll 4
      for (int kk = 0; kk < 24; ++kk) {
        const float2 iv = *(const float2*)&sm[MSGH2 + (k0+kk)*2];
        const float* wp = Wb + (size_t)kk*384;
        const float2 wa = *(const float2*)wp;
        const float2 wb2 = *(const float2*)(wp + 2);
        const float2 wc = *(const float2*)(wp + 4);
        const float ie[2] = {iv.x, iv.y};
        const float we[6] = {wa.x, wa.y, wb2.x, wb2.y, wc.x, wc.y};
        #pragma unroll
        for (int m = 0; m < 2; ++m)
          #pragma unroll
          for (int jj = 0; jj < 6; ++jj)
            acc[m][jj] = fmaf(ie[m], we[jj], acc[m][jj]);
      }
      #pragma unroll
      for (int m = 0; m < 2; ++m) {             // PL overlay [16][384]
        float2 qa = {acc[m][0], acc[m][1]};
        float2 qb = {acc[m][2], acc[m][3]};
        float2 qc = {acc[m][4], acc[m][5]};
        *(float2*)&sm[Z1 + (kq*2 + m)*384 + j6]     = qa;
        *(float2*)&sm[Z1 + (kq*2 + m)*384 + j6 + 2] = qb;
        *(float2*)&sm[Z1 + (kq*2 + m)*384 + j6 + 4] = qc;
      }
    }
    __syncthreads();
    {  // gates reduce (768 entries; gx read from L2)
      #pragma unroll
      for (int t = 0; t < 2; ++t) {
        const int idx = t*512 + tid;            // 0..1023, guard 768
        if (idx < 768) {
          const int m = idx / 384, j = idx - m*384;
          float g = gx[(base+m)*384 + j];
          #pragma unroll
          for (int kq = 0; kq < 8; ++kq) g += sm[Z1 + (kq*2 + m)*384 + j];
          sm[GATES2 + idx] = g;
        }
      }
    }
    __syncthreads();

    // ===== phase 6: pointwise LSTM =====
    if (tid < 192) {
      const int m = tid / 96, hj = tid - m*96;
      const float gi = sm[GATES2 + m*384 + hj];
      const float gf = sm[GATES2 + m*384 + 96 + hj];
      const float gg = sm[GATES2 + m*384 + 192 + hj];
      const float go = sm[GATES2 + m*384 + 288 + hj];
      const float sv = sm[SLC2 + tid];
      const float ig = 1.f/(1.f + expf(-gi));
      const float fg = 1.f/(1.f + expf(-gf));
      const float cg = tanhf(gg);
      const float og = 1.f/(1.f + expf(-go));
      const float s2 = fg*sv + ig*cg;
      const float h2 = og*tanhf(s2);
      sm[SLC2 + tid] = s2;
      sm[H2T2 + hj*2 + m] = h2;
      sm[MSGH2 + (96+hj)*2 + m] = h2;   // h for next step's LSTM GEMM
    }
    __syncthreads();

    // ===== phase 7: u partials (stream msg0_W) =====
    {
      const int jg = tid & 31, kq = tid >> 5;   // 6 cols (192), kq 0..15 x 6k
      const int j6 = jg*6, k0 = kq*6;
      const float* Wb = (j6 < 96) ? (msg0_W + j6) : (msg0_W + 9216 + j6 - 96);
      float acc[2][6] = {{0.f}};
      #pragma unroll
      for (int kk = 0; kk < 6; ++kk) {
        const int k = k0 + kk;
        const float2 hv = *(const float2*)&sm[H2T2 + k*2];
        const float* wp = Wb + k*96;
        const float2 wa = *(const float2*)wp;
        const float2 wb2 = *(const float2*)(wp + 2);
        const float2 wc = *(const float2*)(wp + 4);
        const float he[2] = {hv.x, hv.y};
        const float we[6] = {wa.x, wa.y, wb2.x, wb2.y, wc.x, wc.y};
        #pragma unroll
        for (int m = 0; m < 2; ++m)
          #pragma unroll
          for (int jj = 0; jj < 6; ++jj)
            acc[m][jj] = fmaf(he[m], we[jj], acc[m][jj]);
      }
      #pragma unroll
      for (int m = 0; m < 2; ++m) {             // PU overlay [32][192]
        float2 qa = {acc[m][0], acc[m][1]};
        float2 qb = {acc[m][2], acc[m][3]};
        float2 qc = {acc[m][4], acc[m][5]};
        *(float2*)&sm[Z1 + (kq*2 + m)*192 + j6]     = qa;
        *(float2*)&sm[Z1 + (kq*2 + m)*192 + j6 + 2] = qb;
        *(float2*)&sm[Z1 + (kq*2 + m)*192 + j6 + 4] = qc;
      }
    }
    __syncthreads();
    if (tid < 384) {   // u-write reduce (1 entry each)
      const int m = tid / 192, j = tid - m*192;
      float v = (j >= 96) ? sm[M0B + j - 96] : 0.f;   // fold b0 into self half
      #pragma unroll
      for (int kq = 0; kq < 16; ++kq) v += sm[Z1 + (kq*2 + m)*192 + j];
      uN[(base+m)*192 + j] = v;
    } else {
      // pred head partials (threads 384..511; h2t stable since phase 6; pred_W from L2)
      const int t2 = tid - 384;
      const int m = t2 >> 6, c = (t2 >> 3) & 7, kq2 = t2 & 7;
      float p = 0.f;
      #pragma unroll
      for (int kk = 0; kk < 12; ++kk) {
        const int k = kq2*12 + kk;
        p = fmaf(sm[H2T2 + k*2 + m], pred_W[k*8 + c], p);
      }
      p += __shfl_xor(p, 1);
      p += __shfl_xor(p, 2);
      p += __shfl_xor(p, 4);
      if (kq2 == 0) sm[LGT + m*8 + c] = p + pred_b[c];
    }
    __syncthreads();

    // ===== phase 8: softmax/loss/pred =====
    if (tid < 2) {
      const int m = tid;
      const int node = base + m;
      float mx = sm[LGT + m*8];
      int pred = 0;
      #pragma unroll
      for (int c = 1; c < 8; ++c) {
        const float v = sm[LGT + m*8 + c];
        if (v > mx) { mx = v; pred = c; }
      }
      float sum = 0.f;
      #pragma unroll
      for (int c = 0; c < 8; ++c) sum += expf(sm[LGT + m*8 + c] - mx);
      const float lse = mx + logf(sum);
      const int tgt = target[node] - 1;
      sm[LGT + 16 + m] = lse - sm[LGT + m*8 + tgt];
      sm[LGT + 18 + m] = (pred == tgt) ? 1.f : 0.f;
      if (st == NSTEPS-1) final_pred_out[node] = (float)pred;
      if (m == 0) {
        // lanes 0,1 of this wave wrote above; in-wave instruction order makes this safe
        lossP[st*512 + blk] = sm[LGT+16] + sm[LGT+17];
        cntP[st*512 + blk] = (int)(sm[LGT+18] + sm[LGT+19]);
      }
    }

    // ===== per-batch barrier (32 blocks), ONE fence per block (r3-proven form) =====
    if (st < NSTEPS-1) {
      __syncthreads();   // drains vmcnt for all uN stores
      if (tid == 0) {
        __hip_atomic_fetch_add(&bar[bb*16], 1, __ATOMIC_RELEASE, __HIP_MEMORY_SCOPE_AGENT);
        const int want = 32*(st+1);
        while (__hip_atomic_load(&bar[bb*16], __ATOMIC_RELAXED, __HIP_MEMORY_SCOPE_AGENT) < want)
          __builtin_amdgcn_s_sleep(2);
        __threadfence();   // acquire before reading peers' u (single wave per block)
      }
      __syncthreads();
      const float* tp = uP; uP = uN; uN = (float*)tp;
    }
  }
}

// ---------------- finalize: accs + loss ----------------
__global__ void finalize_kernel(const float* __restrict__ lossP,
                                const int* __restrict__ cntP,
                                float* __restrict__ out)
{
  __shared__ float sl[32];
  const int tid = threadIdx.x;   // 256
  const int st = tid >> 3, q = tid & 7;
  float lsum = 0.f;
  for (int i = 0; i < 64; ++i) lsum += lossP[st*512 + q*64 + i];
  lsum += __shfl_xor(lsum, 1);
  lsum += __shfl_xor(lsum, 2);
  lsum += __shfl_xor(lsum, 4);
  if (q == 0) sl[st] = lsum;
  float okc = 0.f;
  #pragma unroll
  for (int t = 0; t < 2; ++t) {
    const int bbat = q + 8*t;                    // batch id
    int c = 0;
    for (int i = 0; i < 32; ++i) c += cntP[st*512 + i*16 + bbat];  // blocks ≡ bbat (mod 16)
    okc += (c == 64) ? 1.f : 0.f;
  }
  okc += __shfl_xor(okc, 1);
  okc += __shfl_xor(okc, 2);
  okc += __shfl_xor(okc, 4);
  if (q == 0) out[1 + st] = okc / 16.f;
  __syncthreads();
  if (tid == 0) {
    float tot = 0.f;
    for (int i = 0; i < 32; ++i) tot += sl[i];
    out[0] = tot / (1024.f * (float)NSTEPS);
  }
}

extern "C" void kernel_launch(void* const* d_in, const int* in_sizes, int n_in,
                              void* d_out, int out_size, void* d_ws, size_t ws_size,
                              hipStream_t stream) {
  const int*   x         = (const int*)  d_in[0];
  const int*   target    = (const int*)  d_in[1];
  const int*   edges     = (const int*)  d_in[2];
  const float* digit_emb = (const float*)d_in[3];
  const float* row_emb   = (const float*)d_in[4];
  const float* col_emb   = (const float*)d_in[5];
  const float* in0_W     = (const float*)d_in[6];
  const float* in0_b     = (const float*)d_in[7];
  const float* in_Ws     = (const float*)d_in[8];
  const float* in_bs     = (const float*)d_in[9];
  const float* msg0_W    = (const float*)d_in[10];
  const float* msg0_b    = (const float*)d_in[11];
  const float* msg_Ws    = (const float*)d_in[12];
  const float* msg_bs    = (const float*)d_in[13];
  const float* W_ih      = (const float*)d_in[14];
  const float* W_hh      = (const float*)d_in[15];
  const float* b_ih      = (const float*)d_in[16];
  const float* b_hh      = (const float*)d_in[17];
  const float* pred_W    = (const float*)d_in[18];
  const float* pred_b    = (const float*)d_in[19];

  float* ws    = (float*)d_ws;
  float* u0    = ws + WS_U0;
  int*   bar   = (int*)(ws + WS_BAR);
  float* u1    = ws + WS_U1;
  float* xin   = ws + WS_XIN;
  float* gxb   = ws + WS_GX;
  float* lossP = ws + WS_LOSSP;
  int*   cntP  = (int*)(ws + WS_CNTP);

  // zero u0 (edge halves) + barrier counters; everything else fully written
  hipMemsetAsync(d_ws, 0, (size_t)(196608 + 256)*sizeof(float), stream);

  init_kernel<<<1024, HD, 0, stream>>>(x, digit_emb, row_emb, col_emb,
                                       in0_W, in0_b, in_Ws, in_bs,
                                       msg0_b, xin, u0);
  gx_kernel<<<256, 384, 0, stream>>>(xin, W_ih, b_ih, b_hh, gxb);

  float* outp = (float*)d_out;
  solve_kernel<<<512, 512, 0, stream>>>(
      edges, msg0_W, msg0_b, msg_Ws, msg_bs,
      W_ih, W_hh, pred_W, pred_b, target, gxb,
      u0, u1, bar, lossP, cntP, outp + 1 + NSTEPS);

  finalize_kernel<<<1, 256, 0, stream>>>(lossP, cntP, outp);
}